// Round 4
// baseline (650.109 us; speedup 1.0000x reference)
//
#include <hip/hip_runtime.h>
#include <math.h>

// Problem constants
#define BDIM 4096
#define NEXP 8
#define HDIM 1024
#define XDIM 800
#define ZDIM 64
#define ODIM 768
#define GH   128

typedef _Float16 f16;
typedef f16   f16x8 __attribute__((ext_vector_type(8)));
typedef f16   f16x4 __attribute__((ext_vector_type(4)));
typedef float f32x4 __attribute__((ext_vector_type(4)));

__device__ __forceinline__ float elu_act(float x) {
    return x > 0.0f ? x : expm1f(x);
}

__device__ __forceinline__ f16x8 vscale(f16x8 v, f16 s) {
    f16x8 r;
    #pragma unroll
    for (int i = 0; i < 8; ++i) r[i] = v[i] * s;
    return r;
}

// ===========================================================================
// fp32 tiled GEMM with implicit concat input (gating MLP only — small)
// ===========================================================================
#define BMg 64
#define BNg 64
#define BKg 32
#define PADg 68

template<int ACT>
__global__ __launch_bounds__(256)
void gemm_cat(const float* __restrict__ srcA, int KH,
              const float* __restrict__ srcZ, int KZ,
              const float* __restrict__ W, const float* __restrict__ bias,
              float* __restrict__ dst, int N)
{
    __shared__ float lds_a[BKg][PADg];
    __shared__ float lds_b[BKg][PADg];
    const int K = KH + KZ;
    const int row0 = blockIdx.x * BMg;
    const int col0 = blockIdx.y * BNg;
    const int tid = threadIdx.x;
    const int tx = tid & 15, ty = tid >> 4;

    float acc[4][4] = {};

    for (int k0 = 0; k0 < K; k0 += BKg) {
        #pragma unroll
        for (int it = 0; it < 2; ++it) {
            int idx = tid + it * 256;
            int r = idx >> 3;
            int f = idx & 7;
            int k = k0 + f * 4;
            const float* src; int col;
            if (k < KH) { src = srcA + (size_t)(row0 + r) * KH; col = k; }
            else        { src = srcZ + (size_t)(row0 + r) * KZ; col = k - KH; }
            float4 v = *(const float4*)(src + col);
            lds_a[f*4+0][r] = v.x; lds_a[f*4+1][r] = v.y;
            lds_a[f*4+2][r] = v.z; lds_a[f*4+3][r] = v.w;
        }
        #pragma unroll
        for (int it = 0; it < 2; ++it) {
            int idx = tid + it * 256;
            int c = idx >> 3;
            int f = idx & 7;
            int k = k0 + f * 4;
            float4 v = *(const float4*)(W + (size_t)(col0 + c) * K + k);
            lds_b[f*4+0][c] = v.x; lds_b[f*4+1][c] = v.y;
            lds_b[f*4+2][c] = v.z; lds_b[f*4+3][c] = v.w;
        }
        __syncthreads();
        #pragma unroll
        for (int j = 0; j < BKg; ++j) {
            float4 a4 = *(const float4*)&lds_a[j][ty*4];
            float4 b4 = *(const float4*)&lds_b[j][tx*4];
            float a[4] = {a4.x, a4.y, a4.z, a4.w};
            float b[4] = {b4.x, b4.y, b4.z, b4.w};
            #pragma unroll
            for (int i = 0; i < 4; ++i)
                #pragma unroll
                for (int jj = 0; jj < 4; ++jj)
                    acc[i][jj] += a[i] * b[jj];
        }
        __syncthreads();
    }

    #pragma unroll
    for (int i = 0; i < 4; ++i) {
        int r = row0 + ty*4 + i;
        float vals[4];
        #pragma unroll
        for (int j = 0; j < 4; ++j) {
            float v = acc[i][j] + bias[col0 + tx*4 + j];
            vals[j] = (ACT == 1) ? elu_act(v) : v;
        }
        *(float4*)(dst + (size_t)r * N + col0 + tx*4) =
            make_float4(vals[0], vals[1], vals[2], vals[3]);
    }
}

// ===========================================================================
// Gating layer 3 + softmax (fp32)
// ===========================================================================
__global__ __launch_bounds__(256)
void gating3_softmax(const float* __restrict__ g2, const float* __restrict__ Wg3,
                     const float* __restrict__ bg3, float* __restrict__ bc)
{
    __shared__ float w[NEXP * GH];
    __shared__ float bsh[NEXP];
    const int tid = threadIdx.x;
    for (int i = tid; i < NEXP * GH; i += 256) w[i] = Wg3[i];
    if (tid < NEXP) bsh[tid] = bg3[tid];
    __syncthreads();

    const int rowl = tid >> 3;
    const int o    = tid & 7;
    const int row  = blockIdx.x * 32 + rowl;
    const float* g = g2 + (size_t)row * GH;

    float s = bsh[o];
    for (int k = 0; k < GH; ++k) s += g[k] * w[o * GH + k];

    float m = s;
    #pragma unroll
    for (int d = 4; d >= 1; d >>= 1) m = fmaxf(m, __shfl_xor(m, d, 8));
    float e = expf(s - m);
    float sum = e;
    #pragma unroll
    for (int d = 4; d >= 1; d >>= 1) sum += __shfl_xor(sum, d, 8);

    bc[(size_t)blockIdx.x * 256 + tid] = e / sum;
}

// ===========================================================================
// Helper kernels
// ===========================================================================
// Fill z-columns (1024..1087) of both hz buffers with f16(z).
__global__ __launch_bounds__(256)
void fill_z(const float* __restrict__ z, f16* __restrict__ hz_a,
            f16* __restrict__ hz_b)
{
    int i = (blockIdx.x * 256 + threadIdx.x) * 4;      // over 4096*64
    int row = i >> 6;
    int col = i & 63;
    float4 v = *(const float4*)(z + i);
    f16x4 o = { (f16)v.x, (f16)v.y, (f16)v.z, (f16)v.w };
    size_t off = (size_t)row * (HDIM + ZDIM) + HDIM + col;
    *(f16x4*)(hz_a + off) = o;
    *(f16x4*)(hz_b + off) = o;
}

// ===========================================================================
// Weight conversion fp32 -> f16 in MFMA B-frag tiled layout:
//   Wt[(e*(N/16) + nt)*(K/32) + kc][lane][8] where
//   element (lane, j) = W[e][nt*16 + (lane&15)][kc*32 + (lane>>4)*8 + j]
// A wave's B-frag load is then a contiguous, coalesced 1 KB global read.
// Writes fully sequential; reads hit 64B-line granularity.
// ===========================================================================
template<int N, int K>
__global__ __launch_bounds__(256)
void w_tile(const float* __restrict__ W, f16* __restrict__ Wt)
{
    constexpr int KC = K / 32;
    size_t i = (size_t)blockIdx.x * 256 + threadIdx.x;   // one 16B chunk each
    int lane = (int)(i & 63);
    size_t t = i >> 6;
    int kc = (int)(t % KC);
    int nt = (int)((t / KC) % (N / 16));
    int e  = (int)(t / KC / (N / 16));
    const float* s = W + ((size_t)e * N + nt * 16 + (lane & 15)) * K
                       + kc * 32 + (lane >> 4) * 8;
    float4 v0 = *(const float4*)s;
    float4 v1 = *(const float4*)(s + 4);
    f16x8 o = { (f16)v0.x,(f16)v0.y,(f16)v0.z,(f16)v0.w,
                (f16)v1.x,(f16)v1.y,(f16)v1.z,(f16)v1.w };
    *(f16x8*)(Wt + i * 8) = o;
}

// ===========================================================================
// Blended expert layer v2:
//   out[b,o] = act( sum_e (bc[b,e]*A[b,:]) . W[e,o,:] + sum_e bc[b,e]*bias[e,o] )
// - B frags direct global->VGPR from the tiled layout (no LDS, no barrier dep,
//   vmcnt-pipelined). Weight col-slice per XCD ~2.2 MB -> L2-resident.
// - A (64x32 f16 per k-step) in LDS, double-buffered -> ONE barrier per k-step.
// - bc folded into A frags (f16 scale), experts unrolled inside the k-step.
// Tile: 64(M) x 64(N) x 32(K); 4 waves 2x2; per-wave 32x32 via 2x2 MFMA tiles.
// ===========================================================================
template<int K, int N, int ACT, int SRC, typename OT>
__global__ __launch_bounds__(256, 4)
void blended_v2(const f16* __restrict__ A, int ldA,
                const float* __restrict__ x, const float* __restrict__ z,
                const f16* __restrict__ Wt, const float* __restrict__ bias,
                const float* __restrict__ bc, OT* __restrict__ out, int ldOut)
{
    constexpr int KC  = K / 32;
    constexpr int NCT = N / 64;
    // row stride 40 halves (80 B): frag ds_read_b128 2-way bank alias = free
    __shared__ __align__(16) f16 a_sh[2][64][40];
    __shared__ float bc_sh[64][8];
    __shared__ float bias_sh[8][64];

    const int tid  = threadIdx.x;
    const int bid  = blockIdx.x;
    const int row0 = (bid / NCT) * 64;
    const int col0 = (bid % NCT) * 64;   // bid%NCT spreads col-slices over XCDs
    const int wave = tid >> 6;
    const int lane = tid & 63;
    const int ln   = lane & 15;
    const int quad = lane >> 4;
    const int wy   = wave >> 1;          // m half
    const int wx   = wave & 1;           // n half

    // stage bc tile [64][8] and bias tile [8][64]
    for (int i = tid; i < 64 * 8; i += 256)
        bc_sh[i >> 3][i & 7] = bc[(size_t)(row0 + (i >> 3)) * NEXP + (i & 7)];
    for (int i = tid; i < 8 * 64; i += 256)
        bias_sh[i >> 6][i & 63] = bias[(size_t)(i >> 6) * N + col0 + (i & 63)];

    // A staging coords: thread -> (row ar, 8-half chunk ac)
    const int ar = tid >> 2;
    const int ac = tid & 3;

    // A chunk loader for k-step ks (SRC==0: concat(x,z) fp32; else f16 buffer)
    auto loadA = [&](int ks) -> f16x8 {
        int k = ks * 32 + ac * 8;
        if (SRC == 0) {
            const float* s = (k < XDIM)
                ? x + (size_t)(row0 + ar) * XDIM + k
                : z + (size_t)(row0 + ar) * ZDIM + (k - XDIM);
            float4 v0 = *(const float4*)s;
            float4 v1 = *(const float4*)(s + 4);
            return (f16x8){ (f16)v0.x,(f16)v0.y,(f16)v0.z,(f16)v0.w,
                            (f16)v1.x,(f16)v1.y,(f16)v1.z,(f16)v1.w };
        } else {
            return *(const f16x8*)(A + (size_t)(row0 + ar) * ldA + k);
        }
    };

    f16x8 av = loadA(0);

    __syncthreads();   // bc_sh / bias_sh visible

    // per-lane f16 bc scales for A-frag rows (m = wy*32 + mt*16 + ln)
    f16 bcf[2][8];
    #pragma unroll
    for (int mt = 0; mt < 2; ++mt)
        #pragma unroll
        for (int e = 0; e < 8; ++e)
            bcf[mt][e] = (f16)bc_sh[wy*32 + mt*16 + ln][e];

    // B pointer for (e=0, nt=0) frag of this wave; lane-contiguous 16B chunks
    const f16* wp = Wt + ((size_t)(col0/16 + wx*2) * KC) * 512 + lane * 8;
    constexpr size_t ESTR = (size_t)(N/16) * KC * 512;   // expert stride (halves)
    constexpr size_t TSTR = (size_t)KC * 512;            // n-tile stride

    f32x4 acc[2][2] = {};

    for (int ks = 0; ks < KC; ++ks) {
        // stage A[ks] into buffer ks&1 (other buffer still readable last step)
        *(f16x8*)&a_sh[ks & 1][ar][ac * 8] = av;
        __syncthreads();   // single barrier per k-step

        if (ks + 1 < KC) av = loadA(ks + 1);   // in flight across this step

        f16x8 af0 = *(const f16x8*)&a_sh[ks & 1][wy*32 +      ln][quad * 8];
        f16x8 af1 = *(const f16x8*)&a_sh[ks & 1][wy*32 + 16 + ln][quad * 8];

        const f16* wk = wp + (size_t)ks * 512;
        f16x8 b0 = *(const f16x8*)(wk);
        f16x8 b1 = *(const f16x8*)(wk + TSTR);

        #pragma unroll
        for (int e = 0; e < 8; ++e) {
            f16x8 nb0 = b0, nb1 = b1;
            if (e < 7) {
                nb0 = *(const f16x8*)(wk + (size_t)(e+1) * ESTR);
                nb1 = *(const f16x8*)(wk + (size_t)(e+1) * ESTR + TSTR);
            }
            f16x8 s0 = vscale(af0, bcf[0][e]);
            f16x8 s1 = vscale(af1, bcf[1][e]);
            acc[0][0] = __builtin_amdgcn_mfma_f32_16x16x32_f16(s0, b0, acc[0][0], 0,0,0);
            acc[0][1] = __builtin_amdgcn_mfma_f32_16x16x32_f16(s0, b1, acc[0][1], 0,0,0);
            acc[1][0] = __builtin_amdgcn_mfma_f32_16x16x32_f16(s1, b0, acc[1][0], 0,0,0);
            acc[1][1] = __builtin_amdgcn_mfma_f32_16x16x32_f16(s1, b1, acc[1][1], 0,0,0);
            b0 = nb0; b1 = nb1;
        }
    }

    // epilogue: + sum_e bc*bias, activation, store
    #pragma unroll
    for (int mt = 0; mt < 2; ++mt)
        #pragma unroll
        for (int r = 0; r < 4; ++r) {
            int rl = wy*32 + mt*16 + quad*4 + r;
            size_t grow = (size_t)(row0 + rl) * ldOut;
            #pragma unroll
            for (int nt = 0; nt < 2; ++nt) {
                int cl = wx*32 + nt*16 + ln;
                float v = acc[mt][nt][r];
                #pragma unroll
                for (int e2 = 0; e2 < NEXP; ++e2)
                    v += bc_sh[rl][e2] * bias_sh[e2][cl];
                if (ACT) v = elu_act(v);
                out[grow + col0 + cl] = (OT)v;
            }
        }
}

// ===========================================================================
extern "C" void kernel_launch(void* const* d_in, const int* in_sizes, int n_in,
                              void* d_out, int out_size, void* d_ws, size_t ws_size,
                              hipStream_t stream)
{
    const float* x   = (const float*)d_in[0];
    const float* z   = (const float*)d_in[1];
    const float* Wg1 = (const float*)d_in[2];
    const float* bg1 = (const float*)d_in[3];
    const float* Wg2 = (const float*)d_in[4];
    const float* bg2 = (const float*)d_in[5];
    const float* Wg3 = (const float*)d_in[6];
    const float* bg3 = (const float*)d_in[7];
    const float* W0  = (const float*)d_in[8];
    const float* b0  = (const float*)d_in[9];
    const float* W1  = (const float*)d_in[10];
    const float* b1  = (const float*)d_in[11];
    const float* W2  = (const float*)d_in[12];
    const float* b2  = (const float*)d_in[13];
    const float* W3  = (const float*)d_in[14];
    const float* b3  = (const float*)d_in[15];
    float* out = (float*)d_out;

    // workspace (~40 MB): wbuf f16 [8*1024*1088] (reused per layer),
    // hz_a/hz_b f16 [4096][1088], g1/g2 f32 [4096][128], bc f32 [4096][8]
    char* ws = (char*)d_ws;
    f16*   wbuf = (f16*)ws;                 ws += (size_t)NEXP * HDIM * (HDIM + ZDIM) * 2;
    f16*   hz_a = (f16*)ws;                 ws += (size_t)BDIM * (HDIM + ZDIM) * 2;
    f16*   hz_b = (f16*)ws;                 ws += (size_t)BDIM * (HDIM + ZDIM) * 2;
    float* g1   = (float*)ws;               ws += (size_t)BDIM * GH * 4;
    float* g2   = (float*)ws;               ws += (size_t)BDIM * GH * 4;
    float* bcw  = (float*)ws;

    dim3 blk(256);

    // z-columns of hz buffers
    fill_z<<<dim3(BDIM * ZDIM / 4 / 256), blk, 0, stream>>>(z, hz_a, hz_b);

    // gating MLP (fp32)
    gemm_cat<1><<<dim3(BDIM/BMg, GH/BNg), blk, 0, stream>>>(x, XDIM, z, ZDIM, Wg1, bg1, g1, GH);
    gemm_cat<1><<<dim3(BDIM/BMg, GH/BNg), blk, 0, stream>>>(g1, GH, nullptr, 0, Wg2, bg2, g2, GH);
    gating3_softmax<<<dim3(BDIM/32), blk, 0, stream>>>(g2, Wg3, bg3, bcw);

    // blended expert layers: tiled-f16 weight conversion, then frag-direct GEMM
    w_tile<HDIM, XDIM+ZDIM><<<dim3(NEXP*HDIM*(XDIM+ZDIM)/8/256), blk, 0, stream>>>(W0, wbuf);
    blended_v2<XDIM+ZDIM, HDIM, 1, 0, f16><<<dim3(64 * 16), blk, 0, stream>>>(
        nullptr, 0, x, z, wbuf, b0, bcw, hz_a, HDIM + ZDIM);

    w_tile<HDIM, HDIM+ZDIM><<<dim3(NEXP*HDIM*(HDIM+ZDIM)/8/256), blk, 0, stream>>>(W1, wbuf);
    blended_v2<HDIM+ZDIM, HDIM, 1, 1, f16><<<dim3(64 * 16), blk, 0, stream>>>(
        hz_a, HDIM + ZDIM, nullptr, nullptr, wbuf, b1, bcw, hz_b, HDIM + ZDIM);

    w_tile<HDIM, HDIM+ZDIM><<<dim3(NEXP*HDIM*(HDIM+ZDIM)/8/256), blk, 0, stream>>>(W2, wbuf);
    blended_v2<HDIM+ZDIM, HDIM, 1, 1, f16><<<dim3(64 * 16), blk, 0, stream>>>(
        hz_b, HDIM + ZDIM, nullptr, nullptr, wbuf, b2, bcw, hz_a, HDIM + ZDIM);

    w_tile<ODIM, HDIM><<<dim3(NEXP*ODIM*HDIM/8/256), blk, 0, stream>>>(W3, wbuf);
    blended_v2<HDIM, ODIM, 0, 1, float><<<dim3(64 * 12), blk, 0, stream>>>(
        hz_a, HDIM + ZDIM, nullptr, nullptr, wbuf, b3, bcw, out, ODIM);
}